// Round 4
// baseline (18602.199 us; speedup 1.0000x reference)
//
#include <hip/hip_runtime.h>
#include <math.h>

#define TS 256      // time steps
#define NB 256      // batch
#define HD 1024     // hidden dim
#define ID 1024     // input dim

typedef __attribute__((ext_vector_type(8))) short bf16x8;
typedef __attribute__((ext_vector_type(4))) float f32x4;

// fp32 -> (hi, lo) bf16 pair, RNE both. hi+lo reconstructs ~17 mantissa bits.
__device__ __forceinline__ void splitf(float x, int& hi, int& lo) {
  union { float f; unsigned u; } a; a.f = x;
  unsigned t = a.u + 0x7FFFu + ((a.u >> 16) & 1u);
  unsigned hb = t & 0xFFFF0000u;
  union { unsigned u; float f; } hf; hf.u = hb;
  float lf = x - hf.f;
  union { float f; unsigned u; } b; b.f = lf;
  unsigned t2 = b.u + 0x7FFFu + ((b.u >> 16) & 1u);
  hi = (int)(t >> 16);
  lo = (int)(t2 >> 16);
}

// ---------------------------------------------------------------------------
// K0: split fp32 array into bf16 hi/lo arrays. n4 = count/4.
// ---------------------------------------------------------------------------
__global__ __launch_bounds__(256) void k_split(
    const float* __restrict__ src, short* __restrict__ dhi,
    short* __restrict__ dlo, int n4)
{
  int i = blockIdx.x * 256 + threadIdx.x;
  if (i >= n4) return;
  float4 v = ((const float4*)src)[i];
  int h0, h1, h2, h3, l0, l1, l2, l3;
  splitf(v.x, h0, l0); splitf(v.y, h1, l1);
  splitf(v.z, h2, l2); splitf(v.w, h3, l3);
  ((int2*)dhi)[i] = make_int2((h0 & 0xFFFF) | (h1 << 16), (h2 & 0xFFFF) | (h3 << 16));
  ((int2*)dlo)[i] = make_int2((l0 & 0xFFFF) | (l1 << 16), (l2 & 0xFFFF) | (l3 << 16));
}

// ---------------------------------------------------------------------------
// K1: MFMA precompute  A[tl][b][j] = sum_k x[b][t0+tl][k]*Wih[j][k] + bih[j]+bhh[j]
// 3-term bf16 split: xhi*whi + xlo*whi + xhi*wlo.
// Grid ct*16: nb = bid&7 (128-col panel -> per-XCD W_ih L2 residency),
// mbi = bid>>3 (128-row panel: tl = mbi>>1, b0 = (mbi&1)*128).
// 256 threads = 4 waves, wave tile 64x64 (4x4 16x16 quadrants). BK=64.
// LDS: X/W hi+lo tiles [128 rows][8 units of 16B], XOR-swizzled, 64 KB.
// ---------------------------------------------------------------------------
__global__ __launch_bounds__(256) void k_gemm_pre(
    const float* __restrict__ x,
    const short* __restrict__ wih_hi, const short* __restrict__ wih_lo,
    const float* __restrict__ bih, const float* __restrict__ bhh,
    float* __restrict__ A, int t0)
{
  __shared__ uint4 sXh[1024], sXl[1024], sWh[1024], sWl[1024];

  const int tid = threadIdx.x;
  const int bid = blockIdx.x;
  const int nb  = bid & 7;
  const int mbi = bid >> 3;
  const int tl  = mbi >> 1;
  const int b0  = (mbi & 1) * 128;
  const int t   = t0 + tl;
  const int n0  = nb * 128;

  const int l  = tid & 63, wv = tid >> 6;
  const int wm = wv >> 1, wn = wv & 1;
  const int fr = l & 15, fg = l >> 4;

  f32x4 acc[4][4] = {};

  for (int k0 = 0; k0 < ID; k0 += 64) {
    // stage X (fp32 -> split -> LDS) : 1024 units, 4 per thread
    #pragma unroll
    for (int i = 0; i < 4; ++i) {
      int v = tid + i * 256;
      int row = v >> 3, u = v & 7;
      const float* gp = x + ((size_t)(b0 + row) * TS + t) * ID + k0 + u * 8;
      float4 v0 = *(const float4*)gp;
      float4 v1 = *(const float4*)(gp + 4);
      int h0,h1,h2,h3,h4,h5,h6,h7, q0,q1,q2,q3,q4,q5,q6,q7;
      splitf(v0.x,h0,q0); splitf(v0.y,h1,q1); splitf(v0.z,h2,q2); splitf(v0.w,h3,q3);
      splitf(v1.x,h4,q4); splitf(v1.y,h5,q5); splitf(v1.z,h6,q6); splitf(v1.w,h7,q7);
      uint4 ph, pl;
      ph.x=(h0&0xFFFF)|(h1<<16); ph.y=(h2&0xFFFF)|(h3<<16);
      ph.z=(h4&0xFFFF)|(h5<<16); ph.w=(h6&0xFFFF)|(h7<<16);
      pl.x=(q0&0xFFFF)|(q1<<16); pl.y=(q2&0xFFFF)|(q3<<16);
      pl.z=(q4&0xFFFF)|(q5<<16); pl.w=(q6&0xFFFF)|(q7<<16);
      int dst = row * 8 + (u ^ (row & 7));
      sXh[dst] = ph; sXl[dst] = pl;
    }
    // stage W (pre-split bf16): 1024 units each
    #pragma unroll
    for (int i = 0; i < 4; ++i) {
      int v = tid + i * 256;
      int row = v >> 3, u = v & 7;
      size_t so = (size_t)(n0 + row) * ID + k0 + u * 8;
      int dst = row * 8 + (u ^ (row & 7));
      sWh[dst] = *(const uint4*)(wih_hi + so);
      sWl[dst] = *(const uint4*)(wih_lo + so);
    }
    __syncthreads();

    #pragma unroll
    for (int ku = 0; ku < 2; ++ku) {
      bf16x8 xh[4], xl[4], wh[4], wl[4];
      #pragma unroll
      for (int i = 0; i < 4; ++i) {
        int rA = wm * 64 + i * 16 + fr;
        int uA = (ku * 4 + fg) ^ (rA & 7);
        xh[i] = *(const bf16x8*)&sXh[rA * 8 + uA];
        xl[i] = *(const bf16x8*)&sXl[rA * 8 + uA];
        int rB = wn * 64 + i * 16 + fr;
        int uB = (ku * 4 + fg) ^ (rB & 7);
        wh[i] = *(const bf16x8*)&sWh[rB * 8 + uB];
        wl[i] = *(const bf16x8*)&sWl[rB * 8 + uB];
      }
      #pragma unroll
      for (int mt = 0; mt < 4; ++mt)
        #pragma unroll
        for (int nt = 0; nt < 4; ++nt) {
          acc[mt][nt] = __builtin_amdgcn_mfma_f32_16x16x32_bf16(xh[mt], wh[nt], acc[mt][nt], 0,0,0);
          acc[mt][nt] = __builtin_amdgcn_mfma_f32_16x16x32_bf16(xl[mt], wh[nt], acc[mt][nt], 0,0,0);
          acc[mt][nt] = __builtin_amdgcn_mfma_f32_16x16x32_bf16(xh[mt], wl[nt], acc[mt][nt], 0,0,0);
        }
    }
    __syncthreads();
  }

  // epilogue: C/D col = l&15, row = fg*4+g  [verified m89]
  #pragma unroll
  for (int nt = 0; nt < 4; ++nt) {
    int col = n0 + wn * 64 + nt * 16 + fr;
    float bsum = bih[col] + bhh[col];
    #pragma unroll
    for (int mt = 0; mt < 4; ++mt)
      #pragma unroll
      for (int g = 0; g < 4; ++g) {
        int mloc = wm * 64 + mt * 16 + fg * 4 + g;
        A[((size_t)tl * NB + b0 + mloc) * HD + col] = acc[mt][nt][g] + bsum;
      }
  }
}

// ---------------------------------------------------------------------------
// K2: persistent cooperative step kernel.
// 256 blocks x 256 thr (1/CU). Block (nb=bid&31, mb=bid>>5) owns output
// cols nb*32..+32, rows mb*32..+32. W_hh slice (32x1024 hi+lo = 128KB)
// resident in LDS for all steps. Per step: H frags from global (2-deep
// pipelined), 4-term MFMA, tanh+split epilogue, per-mb-group flag sync
// (32 writer blocks; groups independent -> no grid-wide barrier).
// ---------------------------------------------------------------------------
__global__ __launch_bounds__(256) void k_steps(
    const short* __restrict__ whh_hi, const short* __restrict__ whh_lo,
    const float* __restrict__ A,
    short* __restrict__ hh0, short* __restrict__ hl0,
    short* __restrict__ hh1, short* __restrict__ hl1,
    float* __restrict__ hf32, float* __restrict__ last,
    int* __restrict__ flags, int t0, int ct, int cur0)
{
  __shared__ uint4 sWh[4096];   // [32 rows][128 units], swizzled
  __shared__ uint4 sWl[4096];   // 128 KB total

  const int tid = threadIdx.x;
  const int bid = blockIdx.x;
  const int nb  = bid & 31;
  const int mb  = bid >> 5;
  const int l   = tid & 63, wv = tid >> 6;
  const int wm  = wv >> 1, wn = wv & 1;
  const int fr  = l & 15, fg = l >> 4;

  // load W slice once (rows = output cols nb*32..+32)
  for (int i = 0; i < 16; ++i) {
    int v = tid + i * 256;
    int row = v >> 7, u = v & 127;
    int dst = row * 128 + (u ^ (row & 7));
    size_t so = (size_t)(nb * 32 + row) * HD + u * 8;
    sWh[dst] = *(const uint4*)(whh_hi + so);
    sWl[dst] = *(const uint4*)(whh_lo + so);
  }
  __syncthreads();

  const int rowH = mb * 32 + wm * 16 + fr;   // batch row of A-frags
  const int rowW = wn * 16 + fr;             // W LDS row
  const int sw   = rowW & 7;
  const int colC = nb * 32 + wn * 16 + fr;   // output col
  const int mrow0 = mb * 32 + wm * 16 + fg * 4;

  int cur = cur0;
  for (int tl = 0; tl < ct; ++tl) {
    const int t = t0 + tl;
    const short* ghi = cur ? hh1 : hh0;
    const short* glo = cur ? hl1 : hl0;
    short* ohi = cur ? hh0 : hh1;
    short* olo = cur ? hl0 : hl1;
    const float* At = A + (size_t)tl * NB * HD;

    // prefetch epilogue addend (HBM; hidden under MFMA phase)
    float aval[4];
    #pragma unroll
    for (int g = 0; g < 4; ++g)
      aval[g] = At[(size_t)(mrow0 + g) * HD + colC];

    const short* pH = ghi + (size_t)rowH * HD + fg * 8;
    const short* pL = glo + (size_t)rowH * HD + fg * 8;

    f32x4 acc = {0.f, 0.f, 0.f, 0.f};
    bf16x8 fh[3][4], fl[3][4];

    #define LOADG(s, g)                                                     \
      { _Pragma("unroll")                                                   \
        for (int j = 0; j < 4; ++j) {                                       \
          int ku = (g) * 4 + j;                                             \
          fh[s][j] = *(const bf16x8*)(pH + ku * 32);                        \
          fl[s][j] = *(const bf16x8*)(pL + ku * 32);                        \
        } }

    LOADG(0, 0)
    LOADG(1, 1)
    #pragma unroll
    for (int grp = 0; grp < 8; ++grp) {
      const int sc = grp % 3, s2 = (grp + 2) % 3;
      if (grp < 6) LOADG(s2, grp + 2)
      #pragma unroll
      for (int j = 0; j < 4; ++j) {
        int ku = grp * 4 + j;
        int un = (ku * 4 + fg) ^ sw;
        bf16x8 bh = *(const bf16x8*)&sWh[rowW * 128 + un];
        bf16x8 bl = *(const bf16x8*)&sWl[rowW * 128 + un];
        acc = __builtin_amdgcn_mfma_f32_16x16x32_bf16(fh[sc][j], bh, acc, 0,0,0);
        acc = __builtin_amdgcn_mfma_f32_16x16x32_bf16(fh[sc][j], bl, acc, 0,0,0);
        acc = __builtin_amdgcn_mfma_f32_16x16x32_bf16(fl[sc][j], bh, acc, 0,0,0);
        acc = __builtin_amdgcn_mfma_f32_16x16x32_bf16(fl[sc][j], bl, acc, 0,0,0);
      }
    }
    #undef LOADG

    // epilogue
    #pragma unroll
    for (int g = 0; g < 4; ++g) {
      int m = mrow0 + g;
      float hv = tanhf(acc[g] + aval[g]);
      int hi_, lo_; splitf(hv, hi_, lo_);
      size_t off = (size_t)m * HD + colC;
      ohi[off] = (short)hi_;
      olo[off] = (short)lo_;
      if (t == TS - 1) hf32[off] = hv;
      if (m == NB - 1) last[(size_t)t * HD + colC] = hv;
    }

    // per-mb-group sync: 32 writer blocks (nb, mb) -> flag[t*8+mb]
    __threadfence();
    __syncthreads();
    if (tid == 0) {
      int fi = t * 8 + mb;
      __hip_atomic_fetch_add(&flags[fi], 1, __ATOMIC_RELEASE, __HIP_MEMORY_SCOPE_AGENT);
      while (__hip_atomic_load(&flags[fi], __ATOMIC_RELAXED, __HIP_MEMORY_SCOPE_AGENT) < 32)
        __builtin_amdgcn_s_sleep(2);
    }
    __syncthreads();
    __threadfence();   // acquire side
    cur ^= 1;
  }
}

// ---------------------------------------------------------------------------
// K3: out[t][o] = dot(last[t], fc_w[o]) + fc_b[o]
// ---------------------------------------------------------------------------
__global__ __launch_bounds__(256) void k_out(
    const float* __restrict__ last, const float* __restrict__ fcw,
    const float* __restrict__ fcb, float* __restrict__ out)
{
  const int t = blockIdx.x, tid = threadIdx.x;
  float s0 = 0.f, s1 = 0.f;
  for (int j = tid; j < HD; j += 256) {
    float v = last[(size_t)t * HD + j];
    s0 += v * fcw[j];
    s1 += v * fcw[HD + j];
  }
  #pragma unroll
  for (int off = 32; off > 0; off >>= 1) {
    s0 += __shfl_down(s0, off);
    s1 += __shfl_down(s1, off);
  }
  __shared__ float r0[4], r1[4];
  int w = tid >> 6;
  if ((tid & 63) == 0) { r0[w] = s0; r1[w] = s1; }
  __syncthreads();
  if (tid == 0) {
    out[t * 2 + 0] = r0[0] + r0[1] + r0[2] + r0[3] + fcb[0];
    out[t * 2 + 1] = r1[0] + r1[1] + r1[2] + r1[3] + fcb[1];
  }
}

extern "C" void kernel_launch(void* const* d_in, const int* in_sizes, int n_in,
                              void* d_out, int out_size, void* d_ws, size_t ws_size,
                              hipStream_t stream)
{
  const float* x   = (const float*)d_in[0];
  const float* h0  = (const float*)d_in[1];
  const float* Wih = (const float*)d_in[2];
  const float* bih = (const float*)d_in[3];
  const float* Whh = (const float*)d_in[4];
  const float* fcw = (const float*)d_in[6];
  const float* bhh = (const float*)d_in[5];
  const float* fcb = (const float*)d_in[7];
  float* out = (float*)d_out;

  // workspace layout
  float* h    = (float*)d_ws;                       // NB*HD f32 (final h)
  float* last = h + (size_t)NB * HD;                // TS*HD f32
  short* whhh = (short*)(last + (size_t)TS * HD);   // HD*HD
  short* whhl = whhh + (size_t)HD * HD;
  short* wihh = whhl + (size_t)HD * HD;
  short* wihl = wihh + (size_t)HD * HD;
  short* hh0  = wihl + (size_t)HD * HD;             // NB*HD
  short* hl0  = hh0 + (size_t)NB * HD;
  short* hh1  = hl0 + (size_t)NB * HD;
  short* hl1  = hh1 + (size_t)NB * HD;
  int*   flags= (int*)(hl1 + (size_t)NB * HD);      // TS*8
  float* A    = (float*)(flags + TS * 8);

  const size_t per_t = (size_t)NB * HD * sizeof(float);
  const size_t fixed = (size_t)((char*)A - (char*)d_ws);
  int chunkT = TS;
  if (ws_size < fixed + (size_t)TS * per_t) {
    long long avail = (long long)ws_size - (long long)fixed;
    chunkT = (int)(avail / (long long)per_t);
    if (chunkT < 1) chunkT = 1;
    if (chunkT > TS) chunkT = TS;
  }

  hipMemsetAsync(flags, 0, TS * 8 * sizeof(int), stream);
  k_split<<<dim3(HD * HD / 4 / 256), 256, 0, stream>>>(Whh, whhh, whhl, HD * HD / 4);
  k_split<<<dim3(HD * HD / 4 / 256), 256, 0, stream>>>(Wih, wihh, wihl, HD * HD / 4);
  k_split<<<dim3(NB * HD / 4 / 256), 256, 0, stream>>>(h0, hh0, hl0, NB * HD / 4);

  int cur = 0;
  for (int t0 = 0; t0 < TS; t0 += chunkT) {
    const int ct = (chunkT < TS - t0) ? chunkT : (TS - t0);
    k_gemm_pre<<<dim3(ct * 16), 256, 0, stream>>>(x, wihh, wihl, bih, bhh, A, t0);
    void* args[] = {
      (void*)&whhh, (void*)&whhl, (void*)&A,
      (void*)&hh0, (void*)&hl0, (void*)&hh1, (void*)&hl1,
      (void*)&h, (void*)&last, (void*)&flags,
      (void*)&t0, (void*)&ct, (void*)&cur
    };
    hipLaunchCooperativeKernel((void*)k_steps, dim3(256), dim3(256), args, 0, stream);
    cur ^= (ct & 1);
  }
  k_out<<<TS, 256, 0, stream>>>(last, fcw, fcb, out);
  hipMemcpyAsync(out + TS * 2, h, per_t, hipMemcpyDeviceToDevice, stream);
}